// Round 6
// baseline (223.205 us; speedup 1.0000x reference)
//
#include <hip/hip_runtime.h>
#include <math.h>

#define N_NODES 100000
#define N_EDGES 1600000
#define NB 196            // buckets of 512 nodes
#define CAP 12288         // per-bucket edge capacity (mean 8192, sigma~90)
#define CHUNK 4096
#define NBLK_E ((N_EDGES + CHUNK - 1) / CHUNK)   // 391
#define ELDS 1536         // per-block staged edge-index capacity (mean 512, +45 sigma)
#define ENCB ((N_NODES + 63) / 64)               // 1563

typedef __attribute__((ext_vector_type(8))) short bf16x8;
typedef __attribute__((ext_vector_type(4))) float f32x4;
typedef __attribute__((ext_vector_type(2))) float f32x2;

#define SCALE1 16.0f      // hws1 fp8 scaling (dinv[src] NOT baked; applied via f32 fma in agg)
#define SCALE2 256.0f     // hws2 fp8 scaling (dinv baked as before)

// ---------- bf16 helpers ----------
__device__ inline unsigned short f2bf(float f) {
    union { float f; unsigned u; } c; c.f = f;
    unsigned r = c.u + 0x7fffu + ((c.u >> 16) & 1u);
    return (unsigned short)(r >> 16);
}
__device__ inline unsigned pack2(float a, float b) {
    return (unsigned)f2bf(a) | ((unsigned)f2bf(b) << 16);
}

// ---------- fp8 helpers ----------
__device__ inline unsigned f32x4_to_fp8x4(float a, float b, float c, float d) {
    int v = __builtin_amdgcn_cvt_pk_fp8_f32(a, b, 0, false);
    v = __builtin_amdgcn_cvt_pk_fp8_f32(c, d, v, true);
    return (unsigned)v;
}
__device__ inline void add_u2(f32x2* acc, uint2 v) {
    acc[0] += __builtin_amdgcn_cvt_pk_f32_fp8((int)v.x, false);
    acc[1] += __builtin_amdgcn_cvt_pk_f32_fp8((int)v.x, true);
    acc[2] += __builtin_amdgcn_cvt_pk_f32_fp8((int)v.y, false);
    acc[3] += __builtin_amdgcn_cvt_pk_f32_fp8((int)v.y, true);
}
__device__ inline void fma_u4(f32x2* acc, uint4 v, float s) {
    acc[0] += __builtin_amdgcn_cvt_pk_f32_fp8((int)v.x, false) * s;
    acc[1] += __builtin_amdgcn_cvt_pk_f32_fp8((int)v.x, true) * s;
    acc[2] += __builtin_amdgcn_cvt_pk_f32_fp8((int)v.y, false) * s;
    acc[3] += __builtin_amdgcn_cvt_pk_f32_fp8((int)v.y, true) * s;
    acc[4] += __builtin_amdgcn_cvt_pk_f32_fp8((int)v.z, false) * s;
    acc[5] += __builtin_amdgcn_cvt_pk_f32_fp8((int)v.z, true) * s;
    acc[6] += __builtin_amdgcn_cvt_pk_f32_fp8((int)v.w, false) * s;
    acc[7] += __builtin_amdgcn_cvt_pk_f32_fp8((int)v.w, true) * s;
}

// ================= FUSED: edge partition (blocks 0..NBLK_E-1) + weight convert =================
__global__ __launch_bounds__(256) void partconv_kernel(const int* __restrict__ eidx,
                                                       int* __restrict__ gcur,
                                                       unsigned* __restrict__ ebuf,
                                                       const float* __restrict__ Wg0,
                                                       const float* __restrict__ Wg1,
                                                       unsigned short* __restrict__ w0t,
                                                       unsigned short* __restrict__ w1t) {
    __shared__ int lh[NB];
    __shared__ int lbase[NB];
    if (blockIdx.x >= NBLK_E) {
        // ---- wconv: f32 [K][N] -> bf16 col-major [N][K] ----
        int idx = (blockIdx.x - NBLK_E) * 256 + threadIdx.x;
        if (idx < 128 * 128) {
            int n = idx >> 7, k = idx & 127;
            w0t[n * 128 + k] = f2bf(Wg0[k * 128 + n]);
        } else if (idx < 128 * 128 + 64 * 128) {
            int j = idx - 128 * 128;
            int n = j >> 7, k = j & 127;
            w1t[n * 128 + k] = f2bf(Wg1[k * 64 + n]);
        }
        return;
    }
    int tid = threadIdx.x;
    int base = blockIdx.x * CHUNK;
    int d[CHUNK / 256], s[CHUNK / 256];
    for (int i = tid; i < NB; i += 256) lh[i] = 0;
    __syncthreads();
    #pragma unroll
    for (int j = 0; j < CHUNK / 256; j++) {
        int e = base + j * 256 + tid;
        if (e < N_EDGES) {
            d[j] = eidx[N_EDGES + e];
            s[j] = eidx[e];
            atomicAdd(&lh[d[j] >> 9], 1);
        } else d[j] = -1;
    }
    __syncthreads();
    for (int i = tid; i < NB; i += 256) {
        int c = lh[i];
        lbase[i] = c ? (i * CAP + atomicAdd(&gcur[i], c)) : 0;
    }
    __syncthreads();
    for (int i = tid; i < NB; i += 256) lh[i] = 0;
    __syncthreads();
    #pragma unroll
    for (int j = 0; j < CHUNK / 256; j++) {
        if (d[j] >= 0) {
            int b = d[j] >> 9;
            int off = lbase[b] + atomicAdd(&lh[b], 1);
            ebuf[off] = ((unsigned)(d[j] & 511) << 17) | (unsigned)s[j];
        }
    }
}

// ================= FUSED: encoder+layer1 GEMM (blocks 0..ENCB-1) + fine CSR build =================
__global__ __launch_bounds__(256) void enccsr_kernel(const float* __restrict__ x,
                                                     const float* __restrict__ Wenc,
                                                     const float* __restrict__ benc,
                                                     const unsigned short* __restrict__ Wt,
                                                     unsigned char* __restrict__ outb,
                                                     const unsigned* __restrict__ ebuf,
                                                     const int* __restrict__ gcur,
                                                     int* __restrict__ esrc,
                                                     int* __restrict__ cnt,
                                                     int* __restrict__ rowp_end,
                                                     float* __restrict__ dinv) {
    constexpr int PAD = 136;
    __shared__ __align__(16) char smem[128 * PAD * 2 + 64 * PAD * 2];   // 52224 B
    int tid = threadIdx.x;
    if (blockIdx.x < ENCB) {
        // ---------------- encoder + layer-1 GEMM ----------------
        unsigned short* Wl = (unsigned short*)smem;              // 128 x PAD bf16
        unsigned short* hs = (unsigned short*)(smem + 128 * PAD * 2);  // 64 x PAD bf16
        int row0 = blockIdx.x * 64;
        for (int i = tid; i < 128 * 16; i += 256) {
            int n = i >> 4, c = i & 15;
            *(float4*)&Wl[n * PAD + c * 8] = *(const float4*)&Wt[n * 128 + c * 8];
        }
        int wave = tid >> 6, lane = tid & 63;
        int m = lane & 15, quad = lane >> 4;
        int nloc = wave * 16 + m;
        int node = row0 + nloc;
        // ---- phase 1: h0 = relu(x @ W_enc + b) via MFMA (K=16 zero-padded) ----
        bf16x8 xf;
        #pragma unroll
        for (int j = 0; j < 8; j++) xf[j] = 0;
        if (quad < 2 && node < N_NODES) {
            const float* xp = &x[node * 16 + quad * 8];
            #pragma unroll
            for (int j = 0; j < 8; j++) xf[j] = (short)f2bf(xp[j]);
        }
        f32x4 hacc[8];
        #pragma unroll
        for (int t = 0; t < 8; t++) {
            bf16x8 wf;
            #pragma unroll
            for (int j = 0; j < 8; j++) wf[j] = 0;
            if (quad < 2) {
                const float* wp = &Wenc[(quad * 8) * 128 + t * 16 + m];
                #pragma unroll
                for (int j = 0; j < 8; j++) wf[j] = (short)f2bf(wp[j * 128]);
            }
            hacc[t] = __builtin_amdgcn_mfma_f32_16x16x32_bf16(wf, xf, (f32x4){0.f, 0.f, 0.f, 0.f}, 0, 0, 0);
        }
        #pragma unroll
        for (int t = 0; t < 8; t++) {
            int f0 = t * 16 + quad * 4;
            float o0 = fmaxf(hacc[t][0] + benc[f0], 0.f);
            float o1 = fmaxf(hacc[t][1] + benc[f0 + 1], 0.f);
            float o2 = fmaxf(hacc[t][2] + benc[f0 + 2], 0.f);
            float o3 = fmaxf(hacc[t][3] + benc[f0 + 3], 0.f);
            uint2 pk;
            pk.x = pack2(o0, o1);
            pk.y = pack2(o2, o3);
            *(uint2*)&hs[nloc * PAD + f0] = pk;
        }
        __syncthreads();
        // ---- phase 2: hws1 = fp8(SCALE1 * (h0 @ W_g0))  (no dinv baked) ----
        bool nvalid = node < N_NODES;
        f32x4 acc[8];
        #pragma unroll
        for (int t = 0; t < 8; t++) acc[t] = (f32x4){0.f, 0.f, 0.f, 0.f};
        #pragma unroll
        for (int kc = 0; kc < 4; kc++) {
            bf16x8 bfh = *(const bf16x8*)&hs[nloc * PAD + kc * 32 + quad * 8];
            #pragma unroll
            for (int t = 0; t < 8; t++) {
                bf16x8 afw = *(const bf16x8*)&Wl[(t * 16 + m) * PAD + kc * 32 + quad * 8];
                acc[t] = __builtin_amdgcn_mfma_f32_16x16x32_bf16(afw, bfh, acc[t], 0, 0, 0);
            }
        }
        if (nvalid) {
            #pragma unroll
            for (int t = 0; t < 8; t++) {
                unsigned pk = f32x4_to_fp8x4(acc[t][0] * SCALE1, acc[t][1] * SCALE1,
                                             acc[t][2] * SCALE1, acc[t][3] * SCALE1);
                *(unsigned*)&outb[(size_t)node * 128 + t * 16 + quad * 4] = pk;
            }
        }
    } else {
        // ---------------- fine CSR for bucket b ----------------
        int* lcnt = (int*)smem;          // 512
        int* lpre = lcnt + 512;          // 512
        int* wsum = lpre + 512;          // 4
        int b = blockIdx.x - ENCB;
        int beg = b * CAP;
        int end = beg + gcur[b];
        lcnt[tid] = 0; lcnt[tid + 256] = 0;
        __syncthreads();
        for (int e = beg + tid; e < end; e += 256) {
            unsigned v = ebuf[e];
            atomicAdd(&lcnt[v >> 17], 1);
        }
        __syncthreads();
        int a0 = lcnt[2 * tid], a1 = lcnt[2 * tid + 1];
        int ps = a0 + a1;
        int lane = tid & 63, wv = tid >> 6;
        int val = ps;
        #pragma unroll
        for (int off = 1; off < 64; off <<= 1) {
            int n = __shfl_up(val, off, 64);
            if (lane >= off) val += n;
        }
        if (lane == 63) wsum[wv] = val;
        __syncthreads();
        int wbase = 0;
        for (int w = 0; w < wv; w++) wbase += wsum[w];
        int excl = wbase + val - ps;
        lpre[2 * tid] = excl;
        lpre[2 * tid + 1] = excl + a0;
        __syncthreads();
        int node0 = b * 512;
        for (int i = tid; i < 512; i += 256) {
            int node = node0 + i;
            if (node < N_NODES) {
                int c = lcnt[i];
                cnt[node] = c;
                rowp_end[node] = beg + lpre[i] + c;
                dinv[node] = rsqrtf(1.0f + (float)c);
            }
        }
        __syncthreads();
        lcnt[tid] = 0; lcnt[tid + 256] = 0;
        __syncthreads();
        for (int e = beg + tid; e < end; e += 256) {
            unsigned v = ebuf[e];
            int dloc = v >> 17;
            int pos = beg + lpre[dloc] + atomicAdd(&lcnt[dloc], 1);
            esrc[pos] = (int)(v & 0x1FFFFu);
        }
    }
}

// ---------------- FUSED agg layer1 + layer-2 GEMM ----------------
// Block = 32 nodes (4 waves x 8-lane groups). Edge indices staged in LDS, gather
// pipelined 2-deep (8 rows in flight per lane-group). W_g1^T read directly from
// global in phase B (16 KB, L1-hot) so LDS stays at 14.8 KB (occupancy
// LDS-unconstrained). NO launch_bounds waves cap: round-5's (256,6) forced
// VGPR=40 which destroyed the pipeline (needs >=48 VGPR live) — occupancy rose
// but MLP fell, net zero. Natural allocation (~64 VGPR) keeps both.
__global__ __launch_bounds__(256) void agg128gemm_kernel(const unsigned char* __restrict__ hws,
                                                         const int* __restrict__ esrc,
                                                         const int* __restrict__ rowp_end,
                                                         const int* __restrict__ cnt,
                                                         const float* __restrict__ dinv,
                                                         const float* __restrict__ bias,
                                                         const unsigned short* __restrict__ Wt,
                                                         unsigned char* __restrict__ hws2,
                                                         float oscale) {
    constexpr int PAD = 136;
    __shared__ unsigned short hs[32 * PAD];    // h1 tile bf16 (8.7 KB)
    __shared__ int eids[ELDS];                 // staged edge indices (6 KB)
    int tid = threadIdx.x;
    int i0 = blockIdx.x * 32;                  // N_NODES = 3125*32 exactly
    int base = rowp_end[i0] - cnt[i0];
    int brange = rowp_end[i0 + 31] - base;
    int nstage = brange < ELDS ? brange : ELDS;
    for (int k = tid; k < nstage; k += 256) eids[k] = esrc[base + k];

    int wave = tid >> 6, lane = tid & 63;
    int grp = lane >> 3, sub = lane & 7;
    int nloc = wave * 8 + grp;                 // 0..31
    int i = i0 + nloc;
    uint4 selfv = *(const uint4*)&hws[(size_t)i * 128 + sub * 16];
    float di = dinv[i];
    int end = rowp_end[i];
    int start = end - cnt[i];
    __syncthreads();

    // ---- phase A: pipelined gather-aggregate ----
    f32x2 acc[8];
    #pragma unroll
    for (int j = 0; j < 8; j++) acc[j] = (f32x2){0.f, 0.f};
    fma_u4(acc, selfv, di);
    int ls = start - base, le = end - base;
    int lim = le < nstage ? le : nstage;
    int rem = lim - ls;
    int nb = rem >= 4 ? (rem >> 2) : 0;
    int k = ls;
    if (nb > 0) {
        int s0 = eids[k], s1 = eids[k + 1], s2 = eids[k + 2], s3 = eids[k + 3];
        uint4 v0 = *(const uint4*)&hws[(size_t)s0 * 128 + sub * 16];
        uint4 v1 = *(const uint4*)&hws[(size_t)s1 * 128 + sub * 16];
        uint4 v2 = *(const uint4*)&hws[(size_t)s2 * 128 + sub * 16];
        uint4 v3 = *(const uint4*)&hws[(size_t)s3 * 128 + sub * 16];
        float d0 = dinv[s0], d1 = dinv[s1], d2 = dinv[s2], d3 = dinv[s3];
        k += 4;
        for (int it = 1; it < nb; it++) {
            int t0 = eids[k], t1 = eids[k + 1], t2 = eids[k + 2], t3 = eids[k + 3];
            uint4 w0 = *(const uint4*)&hws[(size_t)t0 * 128 + sub * 16];
            uint4 w1 = *(const uint4*)&hws[(size_t)t1 * 128 + sub * 16];
            uint4 w2 = *(const uint4*)&hws[(size_t)t2 * 128 + sub * 16];
            uint4 w3 = *(const uint4*)&hws[(size_t)t3 * 128 + sub * 16];
            float e0 = dinv[t0], e1 = dinv[t1], e2 = dinv[t2], e3 = dinv[t3];
            k += 4;
            fma_u4(acc, v0, d0); fma_u4(acc, v1, d1); fma_u4(acc, v2, d2); fma_u4(acc, v3, d3);
            v0 = w0; v1 = w1; v2 = w2; v3 = w3;
            d0 = e0; d1 = e1; d2 = e2; d3 = e3;
        }
        fma_u4(acc, v0, d0); fma_u4(acc, v1, d1); fma_u4(acc, v2, d2); fma_u4(acc, v3, d3);
    }
    for (; k < lim; k++) {
        int s = eids[k];
        fma_u4(acc, *(const uint4*)&hws[(size_t)s * 128 + sub * 16], dinv[s]);
    }
    for (int k2 = (ls > lim ? ls : lim); k2 < le; k2++) {   // rare: beyond staged capacity
        int s = esrc[base + k2];
        fma_u4(acc, *(const uint4*)&hws[(size_t)s * 128 + sub * 16], dinv[s]);
    }
    {
        float* af = (float*)acc;
        float w = di * (1.0f / SCALE1);
        unsigned pk[8];
        #pragma unroll
        for (int q4 = 0; q4 < 4; q4++) {
            float4 bb = *(const float4*)&bias[sub * 16 + q4 * 4];
            float o0 = fmaxf(bb.x + w * af[q4 * 4 + 0], 0.f);
            float o1 = fmaxf(bb.y + w * af[q4 * 4 + 1], 0.f);
            float o2 = fmaxf(bb.z + w * af[q4 * 4 + 2], 0.f);
            float o3 = fmaxf(bb.w + w * af[q4 * 4 + 3], 0.f);
            pk[q4 * 2] = pack2(o0, o1);
            pk[q4 * 2 + 1] = pack2(o2, o3);
        }
        *(uint4*)&hs[nloc * PAD + sub * 16] = make_uint4(pk[0], pk[1], pk[2], pk[3]);
        *(uint4*)&hs[nloc * PAD + sub * 16 + 8] = make_uint4(pk[4], pk[5], pk[6], pk[7]);
    }
    __syncthreads();
    // ---- phase B: wave = (node-tile tn, col-half ch); W read direct from global (L1-hot) ----
    int m = lane & 15, quad = lane >> 4;
    int tn = wave & 1, ch = wave >> 1;
    int node = i0 + tn * 16 + m;
    f32x4 bacc[2];
    #pragma unroll
    for (int t = 0; t < 2; t++) bacc[t] = (f32x4){0.f, 0.f, 0.f, 0.f};
    #pragma unroll
    for (int kc = 0; kc < 4; kc++) {
        bf16x8 bfh = *(const bf16x8*)&hs[(tn * 16 + m) * PAD + kc * 32 + quad * 8];
        #pragma unroll
        for (int t = 0; t < 2; t++) {
            bf16x8 afw = *(const bf16x8*)&Wt[((ch * 2 + t) * 16 + m) * 128 + kc * 32 + quad * 8];
            bacc[t] = __builtin_amdgcn_mfma_f32_16x16x32_bf16(afw, bfh, bacc[t], 0, 0, 0);
        }
    }
    float d = dinv[node] * oscale;
    #pragma unroll
    for (int t = 0; t < 2; t++) {
        unsigned pk = f32x4_to_fp8x4(bacc[t][0] * d, bacc[t][1] * d, bacc[t][2] * d, bacc[t][3] * d);
        *(unsigned*)&hws2[(size_t)node * 64 + (ch * 2 + t) * 16 + quad * 4] = pk;
    }
}

// ---------------- agg layer2 (F=64, fp8 rows of 64B, dinv baked) + node scoring ----
__global__ __launch_bounds__(256) void agg64_kernel(const unsigned char* __restrict__ hws,
                                                    const int* __restrict__ esrc,
                                                    const int* __restrict__ rowp_end,
                                                    const int* __restrict__ cnt,
                                                    const float* __restrict__ dinv,
                                                    const float* __restrict__ bias,
                                                    const float* __restrict__ Wsw,
                                                    const float* __restrict__ Wv,
                                                    const float* __restrict__ bv,
                                                    float* __restrict__ aarr,
                                                    float* __restrict__ carr,
                                                    float* __restrict__ outv) {
    __shared__ int eids[ELDS];
    int tid = threadIdx.x;
    int wave = tid >> 6, lane = tid & 63;
    int grp = lane >> 3, sub = lane & 7;
    int i0 = blockIdx.x * 32;
    int base = rowp_end[i0] - cnt[i0];
    int brange = rowp_end[i0 + 31] - base;
    int nstage = brange < ELDS ? brange : ELDS;
    for (int k = tid; k < nstage; k += 256) eids[k] = esrc[base + k];
    int i = i0 + wave * 8 + grp;
    uint2 selfv = *(const uint2*)&hws[(size_t)i * 64 + sub * 8];
    float di = dinv[i];
    int end = rowp_end[i];
    int start = end - cnt[i];
    __syncthreads();

    f32x2 acc[4];
    #pragma unroll
    for (int j = 0; j < 4; j++) acc[j] = (f32x2){0.f, 0.f};
    add_u2(acc, selfv);
    int ls = start - base, le = end - base;
    int lim = le < nstage ? le : nstage;
    int rem = lim - ls;
    int nb = rem >= 4 ? (rem >> 2) : 0;
    int k = ls;
    if (nb > 0) {
        int s0 = eids[k], s1 = eids[k + 1], s2 = eids[k + 2], s3 = eids[k + 3];
        uint2 v0 = *(const uint2*)&hws[(size_t)s0 * 64 + sub * 8];
        uint2 v1 = *(const uint2*)&hws[(size_t)s1 * 64 + sub * 8];
        uint2 v2 = *(const uint2*)&hws[(size_t)s2 * 64 + sub * 8];
        uint2 v3 = *(const uint2*)&hws[(size_t)s3 * 64 + sub * 8];
        k += 4;
        for (int it = 1; it < nb; it++) {
            int t0 = eids[k], t1 = eids[k + 1], t2 = eids[k + 2], t3 = eids[k + 3];
            uint2 w0 = *(const uint2*)&hws[(size_t)t0 * 64 + sub * 8];
            uint2 w1 = *(const uint2*)&hws[(size_t)t1 * 64 + sub * 8];
            uint2 w2 = *(const uint2*)&hws[(size_t)t2 * 64 + sub * 8];
            uint2 w3 = *(const uint2*)&hws[(size_t)t3 * 64 + sub * 8];
            k += 4;
            add_u2(acc, v0); add_u2(acc, v1); add_u2(acc, v2); add_u2(acc, v3);
            v0 = w0; v1 = w1; v2 = w2; v3 = w3;
        }
        add_u2(acc, v0); add_u2(acc, v1); add_u2(acc, v2); add_u2(acc, v3);
    }
    for (; k < lim; k++) {
        int s = eids[k];
        add_u2(acc, *(const uint2*)&hws[(size_t)s * 64 + sub * 8]);
    }
    for (int k2 = (ls > lim ? ls : lim); k2 < le; k2++) {
        int s = esrc[base + k2];
        add_u2(acc, *(const uint2*)&hws[(size_t)s * 64 + sub * 8]);
    }
    // ---- scoring (weights loaded now, L1/L2-hot) ----
    float* af = (float*)acc;
    float w = di * (1.0f / SCALE2);
    float pa = 0.f, pc = 0.f, pv = 0.f;
    #pragma unroll
    for (int j = 0; j < 8; j++) {
        int f = sub * 8 + j;
        float h = fmaxf(bias[f] + w * af[j], 0.0f);
        pa += h * Wsw[f];
        pc += h * Wsw[64 + f];
        pv += h * Wv[f];
    }
    #pragma unroll
    for (int m = 1; m <= 4; m <<= 1) {
        pa += __shfl_xor(pa, m, 64);
        pc += __shfl_xor(pc, m, 64);
        pv += __shfl_xor(pv, m, 64);
    }
    if (sub == 0) {
        aarr[i] = pa;
        carr[i] = pc;
        float v = 1.0f / (1.0f + expf(-(pv + bv[0])));
        float t = 0.9f + 0.2f * v;
        float vw = fminf(fmaxf(t * t, 0.81f), 1.21f);
        outv[i] = sqrtf(vw);
    }
}

// ---------------- per-edge switch scores (4 edges/thread) ----------------
__global__ void edge_kernel(const int* __restrict__ eidx, const float* __restrict__ aarr,
                            const float* __restrict__ carr, const float* __restrict__ bsw,
                            float* __restrict__ out) {
    int t = blockIdx.x * 256 + threadIdx.x;
    int e = t * 4;
    if (e + 3 < N_EDGES) {
        int4 s = *(const int4*)&eidx[e];
        int4 d = *(const int4*)&eidx[N_EDGES + e];
        float b = bsw[0];
        float4 o;
        o.x = fminf(fmaxf(1.0f / (1.0f + expf(-(aarr[s.x] + carr[d.x] + b))), 0.0f), 1.0f);
        o.y = fminf(fmaxf(1.0f / (1.0f + expf(-(aarr[s.y] + carr[d.y] + b))), 0.0f), 1.0f);
        o.z = fminf(fmaxf(1.0f / (1.0f + expf(-(aarr[s.z] + carr[d.z] + b))), 0.0f), 1.0f);
        o.w = fminf(fmaxf(1.0f / (1.0f + expf(-(aarr[s.w] + carr[d.w] + b))), 0.0f), 1.0f);
        *(float4*)&out[e] = o;
    } else {
        for (; e < N_EDGES; e++) {
            int s = eidx[e], d = eidx[N_EDGES + e];
            float z = aarr[s] + carr[d] + bsw[0];
            out[e] = fminf(fmaxf(1.0f / (1.0f + expf(-z)), 0.0f), 1.0f);
        }
    }
}

extern "C" void kernel_launch(void* const* d_in, const int* in_sizes, int n_in,
                              void* d_out, int out_size, void* d_ws, size_t ws_size,
                              hipStream_t stream) {
    const float* x     = (const float*)d_in[0];
    const int*   eidx  = (const int*)d_in[1];
    const float* W_enc = (const float*)d_in[2];
    const float* b_enc = (const float*)d_in[3];
    const float* W_g0  = (const float*)d_in[4];
    const float* b_g0  = (const float*)d_in[5];
    const float* W_g1  = (const float*)d_in[6];
    const float* b_g1  = (const float*)d_in[7];
    const float* W_sw  = (const float*)d_in[8];
    const float* b_sw  = (const float*)d_in[9];
    const float* W_v   = (const float*)d_in[10];
    const float* b_v   = (const float*)d_in[11];
    float* out = (float*)d_out;

    char* ws = (char*)d_ws;
    size_t off = 0;
    auto alloc = [&](size_t bytes) {
        void* p = ws + off;
        off = (off + bytes + 255) & ~(size_t)255;
        return p;
    };
    unsigned char*  hws1 = (unsigned char*)alloc((size_t)N_NODES * 128);      // N x 128 fp8
    unsigned char*  hws2 = (unsigned char*)alloc((size_t)N_NODES * 64);       // N x 64 fp8
    int*   cnt  = (int*)alloc((size_t)N_NODES * 4);
    int*   rowp = (int*)alloc((size_t)N_NODES * 4);
    float* dinv = (float*)alloc((size_t)N_NODES * 4);
    float* aarr = (float*)alloc((size_t)N_NODES * 4);
    float* carr = (float*)alloc((size_t)N_NODES * 4);
    int*   esrc = (int*)alloc((size_t)NB * CAP * 4);
    unsigned* ebuf = (unsigned*)alloc((size_t)NB * CAP * 4);
    int*   gcur  = (int*)alloc(256 * 4);
    unsigned short* w0t = (unsigned short*)alloc(128 * 128 * 2);
    unsigned short* w1t = (unsigned short*)alloc(64 * 128 * 2);

    hipMemsetAsync(gcur, 0, NB * 4, stream);
    partconv_kernel<<<NBLK_E + 96, 256, 0, stream>>>(eidx, gcur, ebuf, W_g0, W_g1, w0t, w1t);
    enccsr_kernel<<<ENCB + NB, 256, 0, stream>>>(x, W_enc, b_enc, w0t, hws1,
                                                 ebuf, gcur, esrc, cnt, rowp, dinv);
    agg128gemm_kernel<<<N_NODES / 32, 256, 0, stream>>>(hws1, esrc, rowp, cnt, dinv, b_g0,
                                                        w1t, hws2, SCALE2);
    agg64_kernel<<<(N_NODES + 31) / 32, 256, 0, stream>>>(hws2, esrc, rowp, cnt, dinv, b_g1,
                                                          W_sw, W_v, b_v, aarr, carr, out + N_EDGES);
    edge_kernel<<<(N_EDGES / 4 + 255) / 256, 256, 0, stream>>>(eidx, aarr, carr, b_sw, out);
}

// Round 7
// 222.801 us; speedup vs baseline: 1.0018x; 1.0018x over previous
//
#include <hip/hip_runtime.h>
#include <math.h>

#define N_NODES 100000
#define N_EDGES 1600000
#define NB 196            // buckets of 512 nodes
#define CAP 12288         // per-bucket edge capacity (mean 8192, sigma~90)
#define CHUNK 4096
#define NBLK_E ((N_EDGES + CHUNK - 1) / CHUNK)   // 391
#define ELDS 1280         // per-block staged edge capacity (mean 512, +34 sigma)
#define ENCB ((N_NODES + 63) / 64)               // 1563

typedef __attribute__((ext_vector_type(8))) short bf16x8;
typedef __attribute__((ext_vector_type(4))) float f32x4;
typedef __attribute__((ext_vector_type(2))) float f32x2;

#define SCALE1 16.0f      // hws1 fp8 scaling (dinv[src] NOT baked; applied via f32 fma in agg)
#define SCALE2 256.0f     // hws2 fp8 scaling (dinv baked)

// ---------- bf16 helpers ----------
__device__ inline unsigned short f2bf(float f) {
    union { float f; unsigned u; } c; c.f = f;
    unsigned r = c.u + 0x7fffu + ((c.u >> 16) & 1u);
    return (unsigned short)(r >> 16);
}
__device__ inline unsigned pack2(float a, float b) {
    return (unsigned)f2bf(a) | ((unsigned)f2bf(b) << 16);
}

// ---------- fp8 helpers ----------
__device__ inline unsigned f32x4_to_fp8x4(float a, float b, float c, float d) {
    int v = __builtin_amdgcn_cvt_pk_fp8_f32(a, b, 0, false);
    v = __builtin_amdgcn_cvt_pk_fp8_f32(c, d, v, true);
    return (unsigned)v;
}
__device__ inline void add_u2(f32x2* acc, uint2 v) {
    acc[0] += __builtin_amdgcn_cvt_pk_f32_fp8((int)v.x, false);
    acc[1] += __builtin_amdgcn_cvt_pk_f32_fp8((int)v.x, true);
    acc[2] += __builtin_amdgcn_cvt_pk_f32_fp8((int)v.y, false);
    acc[3] += __builtin_amdgcn_cvt_pk_f32_fp8((int)v.y, true);
}
__device__ inline void fma_u4(f32x2* acc, uint4 v, float s) {
    acc[0] += __builtin_amdgcn_cvt_pk_f32_fp8((int)v.x, false) * s;
    acc[1] += __builtin_amdgcn_cvt_pk_f32_fp8((int)v.x, true) * s;
    acc[2] += __builtin_amdgcn_cvt_pk_f32_fp8((int)v.y, false) * s;
    acc[3] += __builtin_amdgcn_cvt_pk_f32_fp8((int)v.y, true) * s;
    acc[4] += __builtin_amdgcn_cvt_pk_f32_fp8((int)v.z, false) * s;
    acc[5] += __builtin_amdgcn_cvt_pk_f32_fp8((int)v.z, true) * s;
    acc[6] += __builtin_amdgcn_cvt_pk_f32_fp8((int)v.w, false) * s;
    acc[7] += __builtin_amdgcn_cvt_pk_f32_fp8((int)v.w, true) * s;
}

// ================= FUSED: edge partition (blocks 0..NBLK_E-1) + weight convert =================
__global__ __launch_bounds__(256) void partconv_kernel(const int* __restrict__ eidx,
                                                       int* __restrict__ gcur,
                                                       unsigned* __restrict__ ebuf,
                                                       const float* __restrict__ Wg0,
                                                       const float* __restrict__ Wg1,
                                                       unsigned short* __restrict__ w0t,
                                                       unsigned short* __restrict__ w1t) {
    __shared__ int lh[NB];
    __shared__ int lbase[NB];
    if (blockIdx.x >= NBLK_E) {
        // ---- wconv: f32 [K][N] -> bf16 col-major [N][K] ----
        int idx = (blockIdx.x - NBLK_E) * 256 + threadIdx.x;
        if (idx < 128 * 128) {
            int n = idx >> 7, k = idx & 127;
            w0t[n * 128 + k] = f2bf(Wg0[k * 128 + n]);
        } else if (idx < 128 * 128 + 64 * 128) {
            int j = idx - 128 * 128;
            int n = j >> 7, k = j & 127;
            w1t[n * 128 + k] = f2bf(Wg1[k * 64 + n]);
        }
        return;
    }
    int tid = threadIdx.x;
    int base = blockIdx.x * CHUNK;
    int d[16], s[16];
    for (int i = tid; i < NB; i += 256) lh[i] = 0;
    __syncthreads();
    // int4 edge loads: 4 int4-pairs per thread (16 edges). N_EDGES % 4 == 0 so the
    // guard is exact per-quad. CSR build is order-insensitive to this remapping.
    #pragma unroll
    for (int j = 0; j < 4; j++) {
        int idx4 = (base >> 2) + j * 256 + tid;
        if (idx4 * 4 < N_EDGES) {
            int4 sv = ((const int4*)eidx)[idx4];
            int4 dv = ((const int4*)eidx)[(N_EDGES / 4) + idx4];
            s[4 * j + 0] = sv.x; s[4 * j + 1] = sv.y; s[4 * j + 2] = sv.z; s[4 * j + 3] = sv.w;
            d[4 * j + 0] = dv.x; d[4 * j + 1] = dv.y; d[4 * j + 2] = dv.z; d[4 * j + 3] = dv.w;
            atomicAdd(&lh[dv.x >> 9], 1);
            atomicAdd(&lh[dv.y >> 9], 1);
            atomicAdd(&lh[dv.z >> 9], 1);
            atomicAdd(&lh[dv.w >> 9], 1);
        } else {
            d[4 * j + 0] = -1; d[4 * j + 1] = -1; d[4 * j + 2] = -1; d[4 * j + 3] = -1;
        }
    }
    __syncthreads();
    for (int i = tid; i < NB; i += 256) {
        int c = lh[i];
        lbase[i] = c ? (i * CAP + atomicAdd(&gcur[i], c)) : 0;
    }
    __syncthreads();
    for (int i = tid; i < NB; i += 256) lh[i] = 0;
    __syncthreads();
    #pragma unroll
    for (int j = 0; j < 16; j++) {
        if (d[j] >= 0) {
            int b = d[j] >> 9;
            int off = lbase[b] + atomicAdd(&lh[b], 1);
            ebuf[off] = ((unsigned)(d[j] & 511) << 17) | (unsigned)s[j];
        }
    }
}

// ================= FUSED: encoder+layer1 GEMM (blocks 0..ENCB-1) + fine CSR build =================
__global__ __launch_bounds__(256) void enccsr_kernel(const float* __restrict__ x,
                                                     const float* __restrict__ Wenc,
                                                     const float* __restrict__ benc,
                                                     const unsigned short* __restrict__ Wt,
                                                     unsigned char* __restrict__ outb,
                                                     const unsigned* __restrict__ ebuf,
                                                     const int* __restrict__ gcur,
                                                     int* __restrict__ esrc,
                                                     int* __restrict__ cnt,
                                                     int* __restrict__ rowp_end,
                                                     float* __restrict__ dinv) {
    constexpr int PAD = 136;
    __shared__ __align__(16) char smem[128 * PAD * 2 + 64 * PAD * 2];   // 52224 B
    int tid = threadIdx.x;
    if (blockIdx.x < ENCB) {
        // ---------------- encoder + layer-1 GEMM ----------------
        unsigned short* Wl = (unsigned short*)smem;              // 128 x PAD bf16
        unsigned short* hs = (unsigned short*)(smem + 128 * PAD * 2);  // 64 x PAD bf16
        int row0 = blockIdx.x * 64;
        for (int i = tid; i < 128 * 16; i += 256) {
            int n = i >> 4, c = i & 15;
            *(float4*)&Wl[n * PAD + c * 8] = *(const float4*)&Wt[n * 128 + c * 8];
        }
        int wave = tid >> 6, lane = tid & 63;
        int m = lane & 15, quad = lane >> 4;
        int nloc = wave * 16 + m;
        int node = row0 + nloc;
        // ---- phase 1: h0 = relu(x @ W_enc + b) via MFMA (K=16 zero-padded) ----
        bf16x8 xf;
        #pragma unroll
        for (int j = 0; j < 8; j++) xf[j] = 0;
        if (quad < 2 && node < N_NODES) {
            const float* xp = &x[node * 16 + quad * 8];
            #pragma unroll
            for (int j = 0; j < 8; j++) xf[j] = (short)f2bf(xp[j]);
        }
        f32x4 hacc[8];
        #pragma unroll
        for (int t = 0; t < 8; t++) {
            bf16x8 wf;
            #pragma unroll
            for (int j = 0; j < 8; j++) wf[j] = 0;
            if (quad < 2) {
                const float* wp = &Wenc[(quad * 8) * 128 + t * 16 + m];
                #pragma unroll
                for (int j = 0; j < 8; j++) wf[j] = (short)f2bf(wp[j * 128]);
            }
            hacc[t] = __builtin_amdgcn_mfma_f32_16x16x32_bf16(wf, xf, (f32x4){0.f, 0.f, 0.f, 0.f}, 0, 0, 0);
        }
        #pragma unroll
        for (int t = 0; t < 8; t++) {
            int f0 = t * 16 + quad * 4;
            float o0 = fmaxf(hacc[t][0] + benc[f0], 0.f);
            float o1 = fmaxf(hacc[t][1] + benc[f0 + 1], 0.f);
            float o2 = fmaxf(hacc[t][2] + benc[f0 + 2], 0.f);
            float o3 = fmaxf(hacc[t][3] + benc[f0 + 3], 0.f);
            uint2 pk;
            pk.x = pack2(o0, o1);
            pk.y = pack2(o2, o3);
            *(uint2*)&hs[nloc * PAD + f0] = pk;
        }
        __syncthreads();
        // ---- phase 2: hws1 = fp8(SCALE1 * (h0 @ W_g0))  (no dinv baked) ----
        bool nvalid = node < N_NODES;
        f32x4 acc[8];
        #pragma unroll
        for (int t = 0; t < 8; t++) acc[t] = (f32x4){0.f, 0.f, 0.f, 0.f};
        #pragma unroll
        for (int kc = 0; kc < 4; kc++) {
            bf16x8 bfh = *(const bf16x8*)&hs[nloc * PAD + kc * 32 + quad * 8];
            #pragma unroll
            for (int t = 0; t < 8; t++) {
                bf16x8 afw = *(const bf16x8*)&Wl[(t * 16 + m) * PAD + kc * 32 + quad * 8];
                acc[t] = __builtin_amdgcn_mfma_f32_16x16x32_bf16(afw, bfh, acc[t], 0, 0, 0);
            }
        }
        if (nvalid) {
            #pragma unroll
            for (int t = 0; t < 8; t++) {
                unsigned pk = f32x4_to_fp8x4(acc[t][0] * SCALE1, acc[t][1] * SCALE1,
                                             acc[t][2] * SCALE1, acc[t][3] * SCALE1);
                *(unsigned*)&outb[(size_t)node * 128 + t * 16 + quad * 4] = pk;
            }
        }
    } else {
        // ---------------- fine CSR for bucket b ----------------
        int* lcnt = (int*)smem;          // 512
        int* lpre = lcnt + 512;          // 512
        int* wsum = lpre + 512;          // 4
        int b = blockIdx.x - ENCB;
        int beg = b * CAP;
        int end = beg + gcur[b];
        lcnt[tid] = 0; lcnt[tid + 256] = 0;
        __syncthreads();
        for (int e = beg + tid; e < end; e += 256) {
            unsigned v = ebuf[e];
            atomicAdd(&lcnt[v >> 17], 1);
        }
        __syncthreads();
        int a0 = lcnt[2 * tid], a1 = lcnt[2 * tid + 1];
        int ps = a0 + a1;
        int lane = tid & 63, wv = tid >> 6;
        int val = ps;
        #pragma unroll
        for (int off = 1; off < 64; off <<= 1) {
            int n = __shfl_up(val, off, 64);
            if (lane >= off) val += n;
        }
        if (lane == 63) wsum[wv] = val;
        __syncthreads();
        int wbase = 0;
        for (int w = 0; w < wv; w++) wbase += wsum[w];
        int excl = wbase + val - ps;
        lpre[2 * tid] = excl;
        lpre[2 * tid + 1] = excl + a0;
        __syncthreads();
        int node0 = b * 512;
        for (int i = tid; i < 512; i += 256) {
            int node = node0 + i;
            if (node < N_NODES) {
                int c = lcnt[i];
                cnt[node] = c;
                rowp_end[node] = beg + lpre[i] + c;
                dinv[node] = rsqrtf(1.0f + (float)c);
            }
        }
        __syncthreads();
        lcnt[tid] = 0; lcnt[tid + 256] = 0;
        __syncthreads();
        for (int e = beg + tid; e < end; e += 256) {
            unsigned v = ebuf[e];
            int dloc = v >> 17;
            int pos = beg + lpre[dloc] + atomicAdd(&lcnt[dloc], 1);
            esrc[pos] = (int)(v & 0x1FFFFu);
        }
    }
}

// ---------------- FUSED agg layer1 + layer-2 GEMM ----------------
// Block = 32 nodes (4 waves x 8-lane groups). Staging phase gathers BOTH the edge
// index AND dinv[src] into LDS as uint2 pairs (bulk-parallel, off the critical path).
// Inner loop: one ds_read_b64 per edge + one row load — vmem requests per 4-edge
// batch drop 24 -> 16 (the per-edge random dinv gathers are gone), and the FMA's
// scale operand is always LDS-ready. W_g1^T read direct from global in phase B.
__global__ __launch_bounds__(256) void agg128gemm_kernel(const unsigned char* __restrict__ hws,
                                                         const int* __restrict__ esrc,
                                                         const int* __restrict__ rowp_end,
                                                         const int* __restrict__ cnt,
                                                         const float* __restrict__ dinv,
                                                         const float* __restrict__ bias,
                                                         const unsigned short* __restrict__ Wt,
                                                         unsigned char* __restrict__ hws2,
                                                         float oscale) {
    constexpr int PAD = 136;
    __shared__ unsigned short hs[32 * PAD];    // h1 tile bf16 (8.7 KB)
    __shared__ uint2 eidsd[ELDS];              // staged (src, dinv[src]) pairs (10 KB)
    int tid = threadIdx.x;
    int i0 = blockIdx.x * 32;                  // N_NODES = 3125*32 exactly
    int base = rowp_end[i0] - cnt[i0];
    int brange = rowp_end[i0 + 31] - base;
    int nstage = brange < ELDS ? brange : ELDS;
    for (int k = tid; k < nstage; k += 256) {
        int s = esrc[base + k];
        eidsd[k] = make_uint2((unsigned)s, __float_as_uint(dinv[s]));
    }

    int wave = tid >> 6, lane = tid & 63;
    int grp = lane >> 3, sub = lane & 7;
    int nloc = wave * 8 + grp;                 // 0..31
    int i = i0 + nloc;
    uint4 selfv = *(const uint4*)&hws[(size_t)i * 128 + sub * 16];
    float di = dinv[i];
    int end = rowp_end[i];
    int start = end - cnt[i];
    __syncthreads();

    // ---- phase A: pipelined gather-aggregate ----
    f32x2 acc[8];
    #pragma unroll
    for (int j = 0; j < 8; j++) acc[j] = (f32x2){0.f, 0.f};
    fma_u4(acc, selfv, di);
    int ls = start - base, le = end - base;
    int lim = le < nstage ? le : nstage;
    int rem = lim - ls;
    int nb = rem >= 4 ? (rem >> 2) : 0;
    int k = ls;
    if (nb > 0) {
        uint2 p0 = eidsd[k], p1 = eidsd[k + 1], p2 = eidsd[k + 2], p3 = eidsd[k + 3];
        uint4 v0 = *(const uint4*)&hws[(size_t)p0.x * 128 + sub * 16];
        uint4 v1 = *(const uint4*)&hws[(size_t)p1.x * 128 + sub * 16];
        uint4 v2 = *(const uint4*)&hws[(size_t)p2.x * 128 + sub * 16];
        uint4 v3 = *(const uint4*)&hws[(size_t)p3.x * 128 + sub * 16];
        k += 4;
        for (int it = 1; it < nb; it++) {
            uint2 q0 = eidsd[k], q1 = eidsd[k + 1], q2 = eidsd[k + 2], q3 = eidsd[k + 3];
            uint4 w0 = *(const uint4*)&hws[(size_t)q0.x * 128 + sub * 16];
            uint4 w1 = *(const uint4*)&hws[(size_t)q1.x * 128 + sub * 16];
            uint4 w2 = *(const uint4*)&hws[(size_t)q2.x * 128 + sub * 16];
            uint4 w3 = *(const uint4*)&hws[(size_t)q3.x * 128 + sub * 16];
            k += 4;
            fma_u4(acc, v0, __uint_as_float(p0.y));
            fma_u4(acc, v1, __uint_as_float(p1.y));
            fma_u4(acc, v2, __uint_as_float(p2.y));
            fma_u4(acc, v3, __uint_as_float(p3.y));
            v0 = w0; v1 = w1; v2 = w2; v3 = w3;
            p0 = q0; p1 = q1; p2 = q2; p3 = q3;
        }
        fma_u4(acc, v0, __uint_as_float(p0.y));
        fma_u4(acc, v1, __uint_as_float(p1.y));
        fma_u4(acc, v2, __uint_as_float(p2.y));
        fma_u4(acc, v3, __uint_as_float(p3.y));
    }
    for (; k < lim; k++) {
        uint2 p = eidsd[k];
        fma_u4(acc, *(const uint4*)&hws[(size_t)p.x * 128 + sub * 16], __uint_as_float(p.y));
    }
    for (int k2 = (ls > lim ? ls : lim); k2 < le; k2++) {   // rare: beyond staged capacity
        int s = esrc[base + k2];
        fma_u4(acc, *(const uint4*)&hws[(size_t)s * 128 + sub * 16], dinv[s]);
    }
    {
        float* af = (float*)acc;
        float w = di * (1.0f / SCALE1);
        unsigned pk[8];
        #pragma unroll
        for (int q4 = 0; q4 < 4; q4++) {
            float4 bb = *(const float4*)&bias[sub * 16 + q4 * 4];
            float o0 = fmaxf(bb.x + w * af[q4 * 4 + 0], 0.f);
            float o1 = fmaxf(bb.y + w * af[q4 * 4 + 1], 0.f);
            float o2 = fmaxf(bb.z + w * af[q4 * 4 + 2], 0.f);
            float o3 = fmaxf(bb.w + w * af[q4 * 4 + 3], 0.f);
            pk[q4 * 2] = pack2(o0, o1);
            pk[q4 * 2 + 1] = pack2(o2, o3);
        }
        *(uint4*)&hs[nloc * PAD + sub * 16] = make_uint4(pk[0], pk[1], pk[2], pk[3]);
        *(uint4*)&hs[nloc * PAD + sub * 16 + 8] = make_uint4(pk[4], pk[5], pk[6], pk[7]);
    }
    __syncthreads();
    // ---- phase B: wave = (node-tile tn, col-half ch); W read direct from global (L1-hot) ----
    int m = lane & 15, quad = lane >> 4;
    int tn = wave & 1, ch = wave >> 1;
    int node = i0 + tn * 16 + m;
    f32x4 bacc[2];
    #pragma unroll
    for (int t = 0; t < 2; t++) bacc[t] = (f32x4){0.f, 0.f, 0.f, 0.f};
    #pragma unroll
    for (int kc = 0; kc < 4; kc++) {
        bf16x8 bfh = *(const bf16x8*)&hs[(tn * 16 + m) * PAD + kc * 32 + quad * 8];
        #pragma unroll
        for (int t = 0; t < 2; t++) {
            bf16x8 afw = *(const bf16x8*)&Wt[((ch * 2 + t) * 16 + m) * 128 + kc * 32 + quad * 8];
            bacc[t] = __builtin_amdgcn_mfma_f32_16x16x32_bf16(afw, bfh, bacc[t], 0, 0, 0);
        }
    }
    float d = dinv[node] * oscale;
    #pragma unroll
    for (int t = 0; t < 2; t++) {
        unsigned pk = f32x4_to_fp8x4(bacc[t][0] * d, bacc[t][1] * d, bacc[t][2] * d, bacc[t][3] * d);
        *(unsigned*)&hws2[(size_t)node * 64 + (ch * 2 + t) * 16 + quad * 4] = pk;
    }
}

// ---------------- agg layer2 (F=64, fp8 rows of 64B, dinv baked) + node scoring ----
__global__ __launch_bounds__(256) void agg64_kernel(const unsigned char* __restrict__ hws,
                                                    const int* __restrict__ esrc,
                                                    const int* __restrict__ rowp_end,
                                                    const int* __restrict__ cnt,
                                                    const float* __restrict__ dinv,
                                                    const float* __restrict__ bias,
                                                    const float* __restrict__ Wsw,
                                                    const float* __restrict__ Wv,
                                                    const float* __restrict__ bv,
                                                    float* __restrict__ aarr,
                                                    float* __restrict__ carr,
                                                    float* __restrict__ outv) {
    __shared__ int eids[ELDS];
    int tid = threadIdx.x;
    int wave = tid >> 6, lane = tid & 63;
    int grp = lane >> 3, sub = lane & 7;
    int i0 = blockIdx.x * 32;
    int base = rowp_end[i0] - cnt[i0];
    int brange = rowp_end[i0 + 31] - base;
    int nstage = brange < ELDS ? brange : ELDS;
    for (int k = tid; k < nstage; k += 256) eids[k] = esrc[base + k];
    int i = i0 + wave * 8 + grp;
    uint2 selfv = *(const uint2*)&hws[(size_t)i * 64 + sub * 8];
    float di = dinv[i];
    int end = rowp_end[i];
    int start = end - cnt[i];
    __syncthreads();

    f32x2 acc[4];
    #pragma unroll
    for (int j = 0; j < 4; j++) acc[j] = (f32x2){0.f, 0.f};
    add_u2(acc, selfv);
    int ls = start - base, le = end - base;
    int lim = le < nstage ? le : nstage;
    int rem = lim - ls;
    int nb = rem >= 4 ? (rem >> 2) : 0;
    int k = ls;
    if (nb > 0) {
        int s0 = eids[k], s1 = eids[k + 1], s2 = eids[k + 2], s3 = eids[k + 3];
        uint2 v0 = *(const uint2*)&hws[(size_t)s0 * 64 + sub * 8];
        uint2 v1 = *(const uint2*)&hws[(size_t)s1 * 64 + sub * 8];
        uint2 v2 = *(const uint2*)&hws[(size_t)s2 * 64 + sub * 8];
        uint2 v3 = *(const uint2*)&hws[(size_t)s3 * 64 + sub * 8];
        k += 4;
        for (int it = 1; it < nb; it++) {
            int t0 = eids[k], t1 = eids[k + 1], t2 = eids[k + 2], t3 = eids[k + 3];
            uint2 w0 = *(const uint2*)&hws[(size_t)t0 * 64 + sub * 8];
            uint2 w1 = *(const uint2*)&hws[(size_t)t1 * 64 + sub * 8];
            uint2 w2 = *(const uint2*)&hws[(size_t)t2 * 64 + sub * 8];
            uint2 w3 = *(const uint2*)&hws[(size_t)t3 * 64 + sub * 8];
            k += 4;
            add_u2(acc, v0); add_u2(acc, v1); add_u2(acc, v2); add_u2(acc, v3);
            v0 = w0; v1 = w1; v2 = w2; v3 = w3;
        }
        add_u2(acc, v0); add_u2(acc, v1); add_u2(acc, v2); add_u2(acc, v3);
    }
    for (; k < lim; k++) {
        int s = eids[k];
        add_u2(acc, *(const uint2*)&hws[(size_t)s * 64 + sub * 8]);
    }
    for (int k2 = (ls > lim ? ls : lim); k2 < le; k2++) {
        int s = esrc[base + k2];
        add_u2(acc, *(const uint2*)&hws[(size_t)s * 64 + sub * 8]);
    }
    // ---- scoring (weights loaded now, L1/L2-hot) ----
    float* af = (float*)acc;
    float w = di * (1.0f / SCALE2);
    float pa = 0.f, pc = 0.f, pv = 0.f;
    #pragma unroll
    for (int j = 0; j < 8; j++) {
        int f = sub * 8 + j;
        float h = fmaxf(bias[f] + w * af[j], 0.0f);
        pa += h * Wsw[f];
        pc += h * Wsw[64 + f];
        pv += h * Wv[f];
    }
    #pragma unroll
    for (int m = 1; m <= 4; m <<= 1) {
        pa += __shfl_xor(pa, m, 64);
        pc += __shfl_xor(pc, m, 64);
        pv += __shfl_xor(pv, m, 64);
    }
    if (sub == 0) {
        aarr[i] = pa;
        carr[i] = pc;
        float v = 1.0f / (1.0f + expf(-(pv + bv[0])));
        float t = 0.9f + 0.2f * v;
        float vw = fminf(fmaxf(t * t, 0.81f), 1.21f);
        outv[i] = sqrtf(vw);
    }
}

// ---------------- per-edge switch scores (4 edges/thread) ----------------
__global__ void edge_kernel(const int* __restrict__ eidx, const float* __restrict__ aarr,
                            const float* __restrict__ carr, const float* __restrict__ bsw,
                            float* __restrict__ out) {
    int t = blockIdx.x * 256 + threadIdx.x;
    int e = t * 4;
    if (e + 3 < N_EDGES) {
        int4 s = *(const int4*)&eidx[e];
        int4 d = *(const int4*)&eidx[N_EDGES + e];
        float b = bsw[0];
        float4 o;
        o.x = fminf(fmaxf(1.0f / (1.0f + expf(-(aarr[s.x] + carr[d.x] + b))), 0.0f), 1.0f);
        o.y = fminf(fmaxf(1.0f / (1.0f + expf(-(aarr[s.y] + carr[d.y] + b))), 0.0f), 1.0f);
        o.z = fminf(fmaxf(1.0f / (1.0f + expf(-(aarr[s.z] + carr[d.z] + b))), 0.0f), 1.0f);
        o.w = fminf(fmaxf(1.0f / (1.0f + expf(-(aarr[s.w] + carr[d.w] + b))), 0.0f), 1.0f);
        *(float4*)&out[e] = o;
    } else {
        for (; e < N_EDGES; e++) {
            int s = eidx[e], d = eidx[N_EDGES + e];
            float z = aarr[s] + carr[d] + bsw[0];
            out[e] = fminf(fmaxf(1.0f / (1.0f + expf(-z)), 0.0f), 1.0f);
        }
    }
}

extern "C" void kernel_launch(void* const* d_in, const int* in_sizes, int n_in,
                              void* d_out, int out_size, void* d_ws, size_t ws_size,
                              hipStream_t stream) {
    const float* x     = (const float*)d_in[0];
    const int*   eidx  = (const int*)d_in[1];
    const float* W_enc = (const float*)d_in[2];
    const float* b_enc = (const float*)d_in[3];
    const float* W_g0  = (const float*)d_in[4];
    const float* b_g0  = (const float*)d_in[5];
    const float* W_g1  = (const float*)d_in[6];
    const float* b_g1  = (const float*)d_in[7];
    const float* W_sw  = (const float*)d_in[8];
    const float* b_sw  = (const float*)d_in[9];
    const float* W_v   = (const float*)d_in[10];
    const float* b_v   = (const float*)d_in[11];
    float* out = (float*)d_out;

    char* ws = (char*)d_ws;
    size_t off = 0;
    auto alloc = [&](size_t bytes) {
        void* p = ws + off;
        off = (off + bytes + 255) & ~(size_t)255;
        return p;
    };
    unsigned char*  hws1 = (unsigned char*)alloc((size_t)N_NODES * 128);      // N x 128 fp8
    unsigned char*  hws2 = (unsigned char*)alloc((size_t)N_NODES * 64);       // N x 64 fp8
    int*   cnt  = (int*)alloc((size_t)N_NODES * 4);
    int*   rowp = (int*)alloc((size_t)N_NODES * 4);
    float* dinv = (float*)alloc((size_t)N_NODES * 4);
    float* aarr = (float*)alloc((size_t)N_NODES * 4);
    float* carr = (float*)alloc((size_t)N_NODES * 4);
    int*   esrc = (int*)alloc((size_t)NB * CAP * 4);
    unsigned* ebuf = (unsigned*)alloc((size_t)NB * CAP * 4);
    int*   gcur  = (int*)alloc(256 * 4);
    unsigned short* w0t = (unsigned short*)alloc(128 * 128 * 2);
    unsigned short* w1t = (unsigned short*)alloc(64 * 128 * 2);

    hipMemsetAsync(gcur, 0, NB * 4, stream);
    partconv_kernel<<<NBLK_E + 96, 256, 0, stream>>>(eidx, gcur, ebuf, W_g0, W_g1, w0t, w1t);
    enccsr_kernel<<<ENCB + NB, 256, 0, stream>>>(x, W_enc, b_enc, w0t, hws1,
                                                 ebuf, gcur, esrc, cnt, rowp, dinv);
    agg128gemm_kernel<<<N_NODES / 32, 256, 0, stream>>>(hws1, esrc, rowp, cnt, dinv, b_g0,
                                                        w1t, hws2, SCALE2);
    agg64_kernel<<<(N_NODES + 31) / 32, 256, 0, stream>>>(hws2, esrc, rowp, cnt, dinv, b_g1,
                                                          W_sw, W_v, b_v, aarr, carr, out + N_EDGES);
    edge_kernel<<<(N_EDGES / 4 + 255) / 256, 256, 0, stream>>>(eidx, aarr, carr, b_sw, out);
}

// Round 8
// 217.077 us; speedup vs baseline: 1.0282x; 1.0264x over previous
//
#include <hip/hip_runtime.h>
#include <math.h>

#define N_NODES 100000
#define N_EDGES 1600000
#define NB 196            // buckets of 512 nodes
#define CAP 12288         // per-bucket edge capacity (mean 8192, sigma~90)
#define CHUNK 4096
#define NBLK_E ((N_EDGES + CHUNK - 1) / CHUNK)   // 391
#define ELDS 1536         // per-block staged edge-index capacity (mean 512, +45 sigma)
#define ENCB ((N_NODES + 63) / 64)               // 1563

typedef __attribute__((ext_vector_type(8))) short bf16x8;
typedef __attribute__((ext_vector_type(4))) float f32x4;
typedef __attribute__((ext_vector_type(2))) float f32x2;

#define SCALE1 16.0f      // hws1 fp8 scaling (dinv[src] NOT baked; applied via f32 fma in agg)
#define SCALE2 256.0f     // hws2 fp8 scaling (dinv baked)

// ---------- bf16 helpers ----------
__device__ inline unsigned short f2bf(float f) {
    union { float f; unsigned u; } c; c.f = f;
    unsigned r = c.u + 0x7fffu + ((c.u >> 16) & 1u);
    return (unsigned short)(r >> 16);
}
__device__ inline unsigned pack2(float a, float b) {
    return (unsigned)f2bf(a) | ((unsigned)f2bf(b) << 16);
}

// ---------- fp8 helpers ----------
__device__ inline unsigned f32x4_to_fp8x4(float a, float b, float c, float d) {
    int v = __builtin_amdgcn_cvt_pk_fp8_f32(a, b, 0, false);
    v = __builtin_amdgcn_cvt_pk_fp8_f32(c, d, v, true);
    return (unsigned)v;
}
__device__ inline void add_u2(f32x2* acc, uint2 v) {
    acc[0] += __builtin_amdgcn_cvt_pk_f32_fp8((int)v.x, false);
    acc[1] += __builtin_amdgcn_cvt_pk_f32_fp8((int)v.x, true);
    acc[2] += __builtin_amdgcn_cvt_pk_f32_fp8((int)v.y, false);
    acc[3] += __builtin_amdgcn_cvt_pk_f32_fp8((int)v.y, true);
}
__device__ inline void fma_u4(f32x2* acc, uint4 v, float s) {
    acc[0] += __builtin_amdgcn_cvt_pk_f32_fp8((int)v.x, false) * s;
    acc[1] += __builtin_amdgcn_cvt_pk_f32_fp8((int)v.x, true) * s;
    acc[2] += __builtin_amdgcn_cvt_pk_f32_fp8((int)v.y, false) * s;
    acc[3] += __builtin_amdgcn_cvt_pk_f32_fp8((int)v.y, true) * s;
    acc[4] += __builtin_amdgcn_cvt_pk_f32_fp8((int)v.z, false) * s;
    acc[5] += __builtin_amdgcn_cvt_pk_f32_fp8((int)v.z, true) * s;
    acc[6] += __builtin_amdgcn_cvt_pk_f32_fp8((int)v.w, false) * s;
    acc[7] += __builtin_amdgcn_cvt_pk_f32_fp8((int)v.w, true) * s;
}

// ================= FUSED: edge partition (blocks 0..NBLK_E-1) + weight convert =================
__global__ __launch_bounds__(256) void partconv_kernel(const int* __restrict__ eidx,
                                                       int* __restrict__ gcur,
                                                       unsigned* __restrict__ ebuf,
                                                       const float* __restrict__ Wg0,
                                                       const float* __restrict__ Wg1,
                                                       unsigned short* __restrict__ w0t,
                                                       unsigned short* __restrict__ w1t) {
    __shared__ int lh[NB];
    __shared__ int lbase[NB];
    if (blockIdx.x >= NBLK_E) {
        // ---- wconv: f32 [K][N] -> bf16 col-major [N][K] ----
        int idx = (blockIdx.x - NBLK_E) * 256 + threadIdx.x;
        if (idx < 128 * 128) {
            int n = idx >> 7, k = idx & 127;
            w0t[n * 128 + k] = f2bf(Wg0[k * 128 + n]);
        } else if (idx < 128 * 128 + 64 * 128) {
            int j = idx - 128 * 128;
            int n = j >> 7, k = j & 127;
            w1t[n * 128 + k] = f2bf(Wg1[k * 64 + n]);
        }
        return;
    }
    int tid = threadIdx.x;
    int base = blockIdx.x * CHUNK;
    int d[16], s[16];
    for (int i = tid; i < NB; i += 256) lh[i] = 0;
    __syncthreads();
    // int4 edge loads: 4 int4-pairs per thread (16 edges). N_EDGES % 4 == 0 so the
    // guard is exact per-quad. CSR build is order-insensitive to this remapping.
    #pragma unroll
    for (int j = 0; j < 4; j++) {
        int idx4 = (base >> 2) + j * 256 + tid;
        if (idx4 * 4 < N_EDGES) {
            int4 sv = ((const int4*)eidx)[idx4];
            int4 dv = ((const int4*)eidx)[(N_EDGES / 4) + idx4];
            s[4 * j + 0] = sv.x; s[4 * j + 1] = sv.y; s[4 * j + 2] = sv.z; s[4 * j + 3] = sv.w;
            d[4 * j + 0] = dv.x; d[4 * j + 1] = dv.y; d[4 * j + 2] = dv.z; d[4 * j + 3] = dv.w;
            atomicAdd(&lh[dv.x >> 9], 1);
            atomicAdd(&lh[dv.y >> 9], 1);
            atomicAdd(&lh[dv.z >> 9], 1);
            atomicAdd(&lh[dv.w >> 9], 1);
        } else {
            d[4 * j + 0] = -1; d[4 * j + 1] = -1; d[4 * j + 2] = -1; d[4 * j + 3] = -1;
        }
    }
    __syncthreads();
    for (int i = tid; i < NB; i += 256) {
        int c = lh[i];
        lbase[i] = c ? (i * CAP + atomicAdd(&gcur[i], c)) : 0;
    }
    __syncthreads();
    for (int i = tid; i < NB; i += 256) lh[i] = 0;
    __syncthreads();
    #pragma unroll
    for (int j = 0; j < 16; j++) {
        if (d[j] >= 0) {
            int b = d[j] >> 9;
            int off = lbase[b] + atomicAdd(&lh[b], 1);
            ebuf[off] = ((unsigned)(d[j] & 511) << 17) | (unsigned)s[j];
        }
    }
}

// ================= FUSED: encoder+layer1 GEMM (blocks 0..ENCB-1) + fine CSR build =================
__global__ __launch_bounds__(256) void enccsr_kernel(const float* __restrict__ x,
                                                     const float* __restrict__ Wenc,
                                                     const float* __restrict__ benc,
                                                     const unsigned short* __restrict__ Wt,
                                                     unsigned char* __restrict__ outb,
                                                     const unsigned* __restrict__ ebuf,
                                                     const int* __restrict__ gcur,
                                                     int* __restrict__ esrc,
                                                     int* __restrict__ cnt,
                                                     int* __restrict__ rowp_end,
                                                     float* __restrict__ dinv) {
    constexpr int PAD = 136;
    __shared__ __align__(16) char smem[128 * PAD * 2 + 64 * PAD * 2];   // 52224 B
    int tid = threadIdx.x;
    if (blockIdx.x < ENCB) {
        // ---------------- encoder + layer-1 GEMM ----------------
        unsigned short* Wl = (unsigned short*)smem;              // 128 x PAD bf16
        unsigned short* hs = (unsigned short*)(smem + 128 * PAD * 2);  // 64 x PAD bf16
        int row0 = blockIdx.x * 64;
        for (int i = tid; i < 128 * 16; i += 256) {
            int n = i >> 4, c = i & 15;
            *(float4*)&Wl[n * PAD + c * 8] = *(const float4*)&Wt[n * 128 + c * 8];
        }
        int wave = tid >> 6, lane = tid & 63;
        int m = lane & 15, quad = lane >> 4;
        int nloc = wave * 16 + m;
        int node = row0 + nloc;
        // ---- phase 1: h0 = relu(x @ W_enc + b) via MFMA (K=16 zero-padded) ----
        bf16x8 xf;
        #pragma unroll
        for (int j = 0; j < 8; j++) xf[j] = 0;
        if (quad < 2 && node < N_NODES) {
            const float* xp = &x[node * 16 + quad * 8];
            #pragma unroll
            for (int j = 0; j < 8; j++) xf[j] = (short)f2bf(xp[j]);
        }
        f32x4 hacc[8];
        #pragma unroll
        for (int t = 0; t < 8; t++) {
            bf16x8 wf;
            #pragma unroll
            for (int j = 0; j < 8; j++) wf[j] = 0;
            if (quad < 2) {
                const float* wp = &Wenc[(quad * 8) * 128 + t * 16 + m];
                #pragma unroll
                for (int j = 0; j < 8; j++) wf[j] = (short)f2bf(wp[j * 128]);
            }
            hacc[t] = __builtin_amdgcn_mfma_f32_16x16x32_bf16(wf, xf, (f32x4){0.f, 0.f, 0.f, 0.f}, 0, 0, 0);
        }
        #pragma unroll
        for (int t = 0; t < 8; t++) {
            int f0 = t * 16 + quad * 4;
            float o0 = fmaxf(hacc[t][0] + benc[f0], 0.f);
            float o1 = fmaxf(hacc[t][1] + benc[f0 + 1], 0.f);
            float o2 = fmaxf(hacc[t][2] + benc[f0 + 2], 0.f);
            float o3 = fmaxf(hacc[t][3] + benc[f0 + 3], 0.f);
            uint2 pk;
            pk.x = pack2(o0, o1);
            pk.y = pack2(o2, o3);
            *(uint2*)&hs[nloc * PAD + f0] = pk;
        }
        __syncthreads();
        // ---- phase 2: hws1 = fp8(SCALE1 * (h0 @ W_g0))  (no dinv baked) ----
        bool nvalid = node < N_NODES;
        f32x4 acc[8];
        #pragma unroll
        for (int t = 0; t < 8; t++) acc[t] = (f32x4){0.f, 0.f, 0.f, 0.f};
        #pragma unroll
        for (int kc = 0; kc < 4; kc++) {
            bf16x8 bfh = *(const bf16x8*)&hs[nloc * PAD + kc * 32 + quad * 8];
            #pragma unroll
            for (int t = 0; t < 8; t++) {
                bf16x8 afw = *(const bf16x8*)&Wl[(t * 16 + m) * PAD + kc * 32 + quad * 8];
                acc[t] = __builtin_amdgcn_mfma_f32_16x16x32_bf16(afw, bfh, acc[t], 0, 0, 0);
            }
        }
        if (nvalid) {
            #pragma unroll
            for (int t = 0; t < 8; t++) {
                unsigned pk = f32x4_to_fp8x4(acc[t][0] * SCALE1, acc[t][1] * SCALE1,
                                             acc[t][2] * SCALE1, acc[t][3] * SCALE1);
                *(unsigned*)&outb[(size_t)node * 128 + t * 16 + quad * 4] = pk;
            }
        }
    } else {
        // ---------------- fine CSR for bucket b ----------------
        int* lcnt = (int*)smem;          // 512
        int* lpre = lcnt + 512;          // 512
        int* wsum = lpre + 512;          // 4
        int b = blockIdx.x - ENCB;
        int beg = b * CAP;
        int end = beg + gcur[b];
        lcnt[tid] = 0; lcnt[tid + 256] = 0;
        __syncthreads();
        for (int e = beg + tid; e < end; e += 256) {
            unsigned v = ebuf[e];
            atomicAdd(&lcnt[v >> 17], 1);
        }
        __syncthreads();
        int a0 = lcnt[2 * tid], a1 = lcnt[2 * tid + 1];
        int ps = a0 + a1;
        int lane = tid & 63, wv = tid >> 6;
        int val = ps;
        #pragma unroll
        for (int off = 1; off < 64; off <<= 1) {
            int n = __shfl_up(val, off, 64);
            if (lane >= off) val += n;
        }
        if (lane == 63) wsum[wv] = val;
        __syncthreads();
        int wbase = 0;
        for (int w = 0; w < wv; w++) wbase += wsum[w];
        int excl = wbase + val - ps;
        lpre[2 * tid] = excl;
        lpre[2 * tid + 1] = excl + a0;
        __syncthreads();
        int node0 = b * 512;
        for (int i = tid; i < 512; i += 256) {
            int node = node0 + i;
            if (node < N_NODES) {
                int c = lcnt[i];
                cnt[node] = c;
                rowp_end[node] = beg + lpre[i] + c;
                dinv[node] = rsqrtf(1.0f + (float)c);
            }
        }
        __syncthreads();
        lcnt[tid] = 0; lcnt[tid + 256] = 0;
        __syncthreads();
        for (int e = beg + tid; e < end; e += 256) {
            unsigned v = ebuf[e];
            int dloc = v >> 17;
            int pos = beg + lpre[dloc] + atomicAdd(&lcnt[dloc], 1);
            esrc[pos] = (int)(v & 0x1FFFFu);
        }
    }
}

// ---------------- FUSED agg layer1 + layer-2 GEMM ----------------
// Block = 32 nodes (4 waves x 8-lane groups). Edge indices staged in LDS (lgkmcnt path),
// gather pipelined 2-deep. Per-edge dinv[src] gathered from the 400 KB L2-hot table and
// applied via f32 fma. Measured-best config (R3): Wl LDS-staged for phase B (keeping it
// out of L1 which the gather stream needs), no launch-bounds cap (pipeline needs ~60 VGPR;
// forcing occupancy up strangles MLP — R4/R5 A/B).
__global__ __launch_bounds__(256) void agg128gemm_kernel(const unsigned char* __restrict__ hws,
                                                         const int* __restrict__ esrc,
                                                         const int* __restrict__ rowp_end,
                                                         const int* __restrict__ cnt,
                                                         const float* __restrict__ dinv,
                                                         const float* __restrict__ bias,
                                                         const unsigned short* __restrict__ Wt,
                                                         unsigned char* __restrict__ hws2,
                                                         float oscale) {
    constexpr int PAD = 136;
    __shared__ unsigned short Wl[64 * PAD];    // W_g1^T bf16 (17.4 KB)
    __shared__ unsigned short hs[32 * PAD];    // h1 tile bf16 (8.7 KB)
    __shared__ int eids[ELDS];                 // staged edge indices (6 KB)
    int tid = threadIdx.x;
    for (int idx = tid; idx < 64 * 16; idx += 256) {
        int n = idx >> 4, c = idx & 15;
        *(float4*)&Wl[n * PAD + c * 8] = *(const float4*)&Wt[n * 128 + c * 8];
    }
    int i0 = blockIdx.x * 32;                  // N_NODES = 3125*32 exactly
    int base = rowp_end[i0] - cnt[i0];
    int brange = rowp_end[i0 + 31] - base;
    int nstage = brange < ELDS ? brange : ELDS;
    for (int k = tid; k < nstage; k += 256) eids[k] = esrc[base + k];

    int wave = tid >> 6, lane = tid & 63;
    int grp = lane >> 3, sub = lane & 7;
    int nloc = wave * 8 + grp;                 // 0..31
    int i = i0 + nloc;
    uint4 selfv = *(const uint4*)&hws[(size_t)i * 128 + sub * 16];
    float di = dinv[i];
    int end = rowp_end[i];
    int start = end - cnt[i];
    __syncthreads();

    // ---- phase A: pipelined gather-aggregate ----
    f32x2 acc[8];
    #pragma unroll
    for (int j = 0; j < 8; j++) acc[j] = (f32x2){0.f, 0.f};
    fma_u4(acc, selfv, di);
    int ls = start - base, le = end - base;
    int lim = le < nstage ? le : nstage;
    int rem = lim - ls;
    int nb = rem >= 4 ? (rem >> 2) : 0;
    int k = ls;
    if (nb > 0) {
        int s0 = eids[k], s1 = eids[k + 1], s2 = eids[k + 2], s3 = eids[k + 3];
        uint4 v0 = *(const uint4*)&hws[(size_t)s0 * 128 + sub * 16];
        uint4 v1 = *(const uint4*)&hws[(size_t)s1 * 128 + sub * 16];
        uint4 v2 = *(const uint4*)&hws[(size_t)s2 * 128 + sub * 16];
        uint4 v3 = *(const uint4*)&hws[(size_t)s3 * 128 + sub * 16];
        float d0 = dinv[s0], d1 = dinv[s1], d2 = dinv[s2], d3 = dinv[s3];
        k += 4;
        for (int it = 1; it < nb; it++) {
            int t0 = eids[k], t1 = eids[k + 1], t2 = eids[k + 2], t3 = eids[k + 3];
            uint4 w0 = *(const uint4*)&hws[(size_t)t0 * 128 + sub * 16];
            uint4 w1 = *(const uint4*)&hws[(size_t)t1 * 128 + sub * 16];
            uint4 w2 = *(const uint4*)&hws[(size_t)t2 * 128 + sub * 16];
            uint4 w3 = *(const uint4*)&hws[(size_t)t3 * 128 + sub * 16];
            float e0 = dinv[t0], e1 = dinv[t1], e2 = dinv[t2], e3 = dinv[t3];
            k += 4;
            fma_u4(acc, v0, d0); fma_u4(acc, v1, d1); fma_u4(acc, v2, d2); fma_u4(acc, v3, d3);
            v0 = w0; v1 = w1; v2 = w2; v3 = w3;
            d0 = e0; d1 = e1; d2 = e2; d3 = e3;
        }
        fma_u4(acc, v0, d0); fma_u4(acc, v1, d1); fma_u4(acc, v2, d2); fma_u4(acc, v3, d3);
    }
    for (; k < lim; k++) {
        int s = eids[k];
        fma_u4(acc, *(const uint4*)&hws[(size_t)s * 128 + sub * 16], dinv[s]);
    }
    for (int k2 = (ls > lim ? ls : lim); k2 < le; k2++) {   // rare: beyond staged capacity
        int s = esrc[base + k2];
        fma_u4(acc, *(const uint4*)&hws[(size_t)s * 128 + sub * 16], dinv[s]);
    }
    {
        float* af = (float*)acc;
        float w = di * (1.0f / SCALE1);
        unsigned pk[8];
        #pragma unroll
        for (int q4 = 0; q4 < 4; q4++) {
            float4 bb = *(const float4*)&bias[sub * 16 + q4 * 4];
            float o0 = fmaxf(bb.x + w * af[q4 * 4 + 0], 0.f);
            float o1 = fmaxf(bb.y + w * af[q4 * 4 + 1], 0.f);
            float o2 = fmaxf(bb.z + w * af[q4 * 4 + 2], 0.f);
            float o3 = fmaxf(bb.w + w * af[q4 * 4 + 3], 0.f);
            pk[q4 * 2] = pack2(o0, o1);
            pk[q4 * 2 + 1] = pack2(o2, o3);
        }
        *(uint4*)&hs[nloc * PAD + sub * 16] = make_uint4(pk[0], pk[1], pk[2], pk[3]);
        *(uint4*)&hs[nloc * PAD + sub * 16 + 8] = make_uint4(pk[4], pk[5], pk[6], pk[7]);
    }
    __syncthreads();
    // ---- phase B: wave = (node-tile tn, col-half ch); 2 out-tiles x 4 k-chunks each ----
    int m = lane & 15, quad = lane >> 4;
    int tn = wave & 1, ch = wave >> 1;
    int node = i0 + tn * 16 + m;
    f32x4 bacc[2];
    #pragma unroll
    for (int t = 0; t < 2; t++) bacc[t] = (f32x4){0.f, 0.f, 0.f, 0.f};
    #pragma unroll
    for (int kc = 0; kc < 4; kc++) {
        bf16x8 bfh = *(const bf16x8*)&hs[(tn * 16 + m) * PAD + kc * 32 + quad * 8];
        #pragma unroll
        for (int t = 0; t < 2; t++) {
            bf16x8 afw = *(const bf16x8*)&Wl[((ch * 2 + t) * 16 + m) * PAD + kc * 32 + quad * 8];
            bacc[t] = __builtin_amdgcn_mfma_f32_16x16x32_bf16(afw, bfh, bacc[t], 0, 0, 0);
        }
    }
    float d = dinv[node] * oscale;
    #pragma unroll
    for (int t = 0; t < 2; t++) {
        unsigned pk = f32x4_to_fp8x4(bacc[t][0] * d, bacc[t][1] * d, bacc[t][2] * d, bacc[t][3] * d);
        *(unsigned*)&hws2[(size_t)node * 64 + (ch * 2 + t) * 16 + quad * 4] = pk;
    }
}

// ---------------- agg layer2 (F=64, fp8 rows of 64B, dinv baked) + node scoring ----
__global__ __launch_bounds__(256) void agg64_kernel(const unsigned char* __restrict__ hws,
                                                    const int* __restrict__ esrc,
                                                    const int* __restrict__ rowp_end,
                                                    const int* __restrict__ cnt,
                                                    const float* __restrict__ dinv,
                                                    const float* __restrict__ bias,
                                                    const float* __restrict__ Wsw,
                                                    const float* __restrict__ Wv,
                                                    const float* __restrict__ bv,
                                                    float* __restrict__ aarr,
                                                    float* __restrict__ carr,
                                                    float* __restrict__ outv) {
    __shared__ int eids[ELDS];
    int tid = threadIdx.x;
    int wave = tid >> 6, lane = tid & 63;
    int grp = lane >> 3, sub = lane & 7;
    int i0 = blockIdx.x * 32;
    int base = rowp_end[i0] - cnt[i0];
    int brange = rowp_end[i0 + 31] - base;
    int nstage = brange < ELDS ? brange : ELDS;
    for (int k = tid; k < nstage; k += 256) eids[k] = esrc[base + k];
    int i = i0 + wave * 8 + grp;
    uint2 selfv = *(const uint2*)&hws[(size_t)i * 64 + sub * 8];
    float di = dinv[i];
    int end = rowp_end[i];
    int start = end - cnt[i];
    __syncthreads();

    f32x2 acc[4];
    #pragma unroll
    for (int j = 0; j < 4; j++) acc[j] = (f32x2){0.f, 0.f};
    add_u2(acc, selfv);
    int ls = start - base, le = end - base;
    int lim = le < nstage ? le : nstage;
    int rem = lim - ls;
    int nb = rem >= 4 ? (rem >> 2) : 0;
    int k = ls;
    if (nb > 0) {
        int s0 = eids[k], s1 = eids[k + 1], s2 = eids[k + 2], s3 = eids[k + 3];
        uint2 v0 = *(const uint2*)&hws[(size_t)s0 * 64 + sub * 8];
        uint2 v1 = *(const uint2*)&hws[(size_t)s1 * 64 + sub * 8];
        uint2 v2 = *(const uint2*)&hws[(size_t)s2 * 64 + sub * 8];
        uint2 v3 = *(const uint2*)&hws[(size_t)s3 * 64 + sub * 8];
        k += 4;
        for (int it = 1; it < nb; it++) {
            int t0 = eids[k], t1 = eids[k + 1], t2 = eids[k + 2], t3 = eids[k + 3];
            uint2 w0 = *(const uint2*)&hws[(size_t)t0 * 64 + sub * 8];
            uint2 w1 = *(const uint2*)&hws[(size_t)t1 * 64 + sub * 8];
            uint2 w2 = *(const uint2*)&hws[(size_t)t2 * 64 + sub * 8];
            uint2 w3 = *(const uint2*)&hws[(size_t)t3 * 64 + sub * 8];
            k += 4;
            add_u2(acc, v0); add_u2(acc, v1); add_u2(acc, v2); add_u2(acc, v3);
            v0 = w0; v1 = w1; v2 = w2; v3 = w3;
        }
        add_u2(acc, v0); add_u2(acc, v1); add_u2(acc, v2); add_u2(acc, v3);
    }
    for (; k < lim; k++) {
        int s = eids[k];
        add_u2(acc, *(const uint2*)&hws[(size_t)s * 64 + sub * 8]);
    }
    for (int k2 = (ls > lim ? ls : lim); k2 < le; k2++) {
        int s = esrc[base + k2];
        add_u2(acc, *(const uint2*)&hws[(size_t)s * 64 + sub * 8]);
    }
    // ---- scoring (weights loaded now, L1/L2-hot) ----
    float* af = (float*)acc;
    float w = di * (1.0f / SCALE2);
    float pa = 0.f, pc = 0.f, pv = 0.f;
    #pragma unroll
    for (int j = 0; j < 8; j++) {
        int f = sub * 8 + j;
        float h = fmaxf(bias[f] + w * af[j], 0.0f);
        pa += h * Wsw[f];
        pc += h * Wsw[64 + f];
        pv += h * Wv[f];
    }
    #pragma unroll
    for (int m = 1; m <= 4; m <<= 1) {
        pa += __shfl_xor(pa, m, 64);
        pc += __shfl_xor(pc, m, 64);
        pv += __shfl_xor(pv, m, 64);
    }
    if (sub == 0) {
        aarr[i] = pa;
        carr[i] = pc;
        float v = 1.0f / (1.0f + expf(-(pv + bv[0])));
        float t = 0.9f + 0.2f * v;
        float vw = fminf(fmaxf(t * t, 0.81f), 1.21f);
        outv[i] = sqrtf(vw);
    }
}

// ---------------- per-edge switch scores (4 edges/thread) ----------------
__global__ void edge_kernel(const int* __restrict__ eidx, const float* __restrict__ aarr,
                            const float* __restrict__ carr, const float* __restrict__ bsw,
                            float* __restrict__ out) {
    int t = blockIdx.x * 256 + threadIdx.x;
    int e = t * 4;
    if (e + 3 < N_EDGES) {
        int4 s = *(const int4*)&eidx[e];
        int4 d = *(const int4*)&eidx[N_EDGES + e];
        float b = bsw[0];
        float4 o;
        o.x = fminf(fmaxf(1.0f / (1.0f + expf(-(aarr[s.x] + carr[d.x] + b))), 0.0f), 1.0f);
        o.y = fminf(fmaxf(1.0f / (1.0f + expf(-(aarr[s.y] + carr[d.y] + b))), 0.0f), 1.0f);
        o.z = fminf(fmaxf(1.0f / (1.0f + expf(-(aarr[s.z] + carr[d.z] + b))), 0.0f), 1.0f);
        o.w = fminf(fmaxf(1.0f / (1.0f + expf(-(aarr[s.w] + carr[d.w] + b))), 0.0f), 1.0f);
        *(float4*)&out[e] = o;
    } else {
        for (; e < N_EDGES; e++) {
            int s = eidx[e], d = eidx[N_EDGES + e];
            float z = aarr[s] + carr[d] + bsw[0];
            out[e] = fminf(fmaxf(1.0f / (1.0f + expf(-z)), 0.0f), 1.0f);
        }
    }
}

extern "C" void kernel_launch(void* const* d_in, const int* in_sizes, int n_in,
                              void* d_out, int out_size, void* d_ws, size_t ws_size,
                              hipStream_t stream) {
    const float* x     = (const float*)d_in[0];
    const int*   eidx  = (const int*)d_in[1];
    const float* W_enc = (const float*)d_in[2];
    const float* b_enc = (const float*)d_in[3];
    const float* W_g0  = (const float*)d_in[4];
    const float* b_g0  = (const float*)d_in[5];
    const float* W_g1  = (const float*)d_in[6];
    const float* b_g1  = (const float*)d_in[7];
    const float* W_sw  = (const float*)d_in[8];
    const float* b_sw  = (const float*)d_in[9];
    const float* W_v   = (const float*)d_in[10];
    const float* b_v   = (const float*)d_in[11];
    float* out = (float*)d_out;

    char* ws = (char*)d_ws;
    size_t off = 0;
    auto alloc = [&](size_t bytes) {
        void* p = ws + off;
        off = (off + bytes + 255) & ~(size_t)255;
        return p;
    };
    unsigned char*  hws1 = (unsigned char*)alloc((size_t)N_NODES * 128);      // N x 128 fp8
    unsigned char*  hws2 = (unsigned char*)alloc((size_t)N_NODES * 64);       // N x 64 fp8
    int*   cnt  = (int*)alloc((size_t)N_NODES * 4);
    int*   rowp = (int*)alloc((size_t)N_NODES * 4);
    float* dinv = (float*)alloc((size_t)N_NODES * 4);
    float* aarr = (float*)alloc((size_t)N_NODES * 4);
    float* carr = (float*)alloc((size_t)N_NODES * 4);
    int*   esrc = (int*)alloc((size_t)NB * CAP * 4);
    unsigned* ebuf = (unsigned*)alloc((size_t)NB * CAP * 4);
    int*   gcur  = (int*)alloc(256 * 4);
    unsigned short* w0t = (unsigned short*)alloc(128 * 128 * 2);
    unsigned short* w1t = (unsigned short*)alloc(64 * 128 * 2);

    hipMemsetAsync(gcur, 0, NB * 4, stream);
    partconv_kernel<<<NBLK_E + 96, 256, 0, stream>>>(eidx, gcur, ebuf, W_g0, W_g1, w0t, w1t);
    enccsr_kernel<<<ENCB + NB, 256, 0, stream>>>(x, W_enc, b_enc, w0t, hws1,
                                                 ebuf, gcur, esrc, cnt, rowp, dinv);
    agg128gemm_kernel<<<N_NODES / 32, 256, 0, stream>>>(hws1, esrc, rowp, cnt, dinv, b_g0,
                                                        w1t, hws2, SCALE2);
    agg64_kernel<<<(N_NODES + 31) / 32, 256, 0, stream>>>(hws2, esrc, rowp, cnt, dinv, b_g1,
                                                          W_sw, W_v, b_v, aarr, carr, out + N_EDGES);
    edge_kernel<<<(N_EDGES / 4 + 255) / 256, 256, 0, stream>>>(eidx, aarr, carr, b_sw, out);
}